// Round 1
// baseline (48509.232 us; speedup 1.0000x reference)
//
#include <hip/hip_runtime.h>

// ---------------------------------------------------------------------------
// Model dims
// ---------------------------------------------------------------------------
#define BB     256
#define TSEED  120
#define PREDN  24
#define JN     15
#define HN     1024
#define DN     135
#define FN     61      // rfft bins = TSEED/2+1
#define TT     144     // T_SEED + PRED
#define DH     256     // head dim
#define BCH    32      // encoder batch chunk
#define RCH    (BCH*FN)   // rows per chunk = 1952

// ---------------------------------------------------------------------------
// cos matrix for real part of rfft:  C[f][t] = cos(2*pi*f*t/120)
// ---------------------------------------------------------------------------
__global__ __launch_bounds__(128) void cos_kernel(float* __restrict__ cosm) {
    int f = blockIdx.x, t = threadIdx.x;
    if (t < TSEED) {
        int ft = (f * t) % TSEED;
        float ang = (float)ft * (6.283185307179586f / (float)TSEED);
        cosm[f * TSEED + t] = cosf(ang);
    }
}

// ---------------------------------------------------------------------------
// DFT: freq[bl][f][d] = sum_t poses[b][t][d] * C[f][t]   (one block per batch)
// ---------------------------------------------------------------------------
__global__ __launch_bounds__(256) void dft_kernel(const float* __restrict__ poses,
                                                  const float* __restrict__ cosm,
                                                  float* __restrict__ freq) {
    __shared__ float cs[FN * TSEED];
    for (int i = threadIdx.x; i < FN * TSEED; i += 256) cs[i] = cosm[i];
    __syncthreads();
    const float* xp = poses + (size_t)blockIdx.x * TT * DN;
    float* fp = freq + (size_t)blockIdx.x * FN * DN;
    for (int o = threadIdx.x; o < FN * DN; o += 256) {
        int f = o / DN, d = o - f * DN;
        const float* cf = &cs[f * TSEED];
        float s = 0.f;
        #pragma unroll 4
        for (int t = 0; t < TSEED; ++t) s += xp[t * DN + d] * cf[t];
        fp[o] = s;
    }
}

// ---------------------------------------------------------------------------
// Generic fp32 GEMM: C[m][n] = ACT(sum_k A[m][k]*B[n][k] + bias[n]) (+ addm)
// 64x64 tile, 256 threads, 4x4 per thread, TK=16 (k-major LDS, float4 reads)
// ---------------------------------------------------------------------------
template<int ACT, int HASADD>
__global__ __launch_bounds__(256) void gemm_bt(const float* __restrict__ A, int lda,
                                               const float* __restrict__ Bw, int ldb,
                                               const float* __restrict__ bias,
                                               const float* __restrict__ addm,
                                               float* __restrict__ C,
                                               int M, int N, int K) {
    __shared__ float As[16][68];
    __shared__ float Bs[16][68];
    const int m0 = blockIdx.x * 64, n0 = blockIdx.y * 64;
    const int tid = threadIdx.x;
    const int tx = tid & 15, ty = tid >> 4;
    const int lrow = tid >> 2, lk = (tid & 3) * 4;
    float acc[4][4] = {{0.f}};
    for (int k0 = 0; k0 < K; k0 += 16) {
        #pragma unroll
        for (int i = 0; i < 4; ++i) {
            int k = k0 + lk + i;
            int m = m0 + lrow, n = n0 + lrow;
            As[lk + i][lrow] = (m < M && k < K) ? A[(size_t)m * lda + k] : 0.f;
            Bs[lk + i][lrow] = (n < N && k < K) ? Bw[(size_t)n * ldb + k] : 0.f;
        }
        __syncthreads();
        #pragma unroll
        for (int kk = 0; kk < 16; ++kk) {
            float a[4], b[4];
            *(float4*)a = *(const float4*)&As[kk][ty * 4];
            *(float4*)b = *(const float4*)&Bs[kk][tx * 4];
            #pragma unroll
            for (int i = 0; i < 4; ++i)
                #pragma unroll
                for (int j = 0; j < 4; ++j)
                    acc[i][j] += a[i] * b[j];
        }
        __syncthreads();
    }
    #pragma unroll
    for (int i = 0; i < 4; ++i) {
        int m = m0 + ty * 4 + i;
        if (m >= M) continue;
        #pragma unroll
        for (int j = 0; j < 4; ++j) {
            int n = n0 + tx * 4 + j;
            if (n >= N) continue;
            float v = acc[i][j] + bias[n];
            if (ACT) v = fmaxf(v, 0.f);
            if (HASADD) v += addm[(size_t)m * N + n];
            C[(size_t)m * N + n] = v;
        }
    }
}

// ---------------------------------------------------------------------------
// Attention for one (batch, head); accumulates mean_t(o) into obar.
// qkv rows are the chunk's (bl*61+t), channels [q|k|v] each HN wide.
// ---------------------------------------------------------------------------
__global__ __launch_bounds__(256) void attn_kernel(const float* __restrict__ qkv,
                                                   float* __restrict__ obar, int b0) {
    __shared__ float Qs[FN][DH];
    __shared__ float Ks[FN][DH];
    __shared__ float Ss[FN][62];
    const int bl = blockIdx.x, h = blockIdx.y;
    const float* base = qkv + (size_t)bl * FN * 3 * HN + h * DH;
    for (int i = threadIdx.x; i < FN * DH; i += 256) {
        int t = i >> 8, d = i & 255;
        Qs[t][d] = base[(size_t)t * 3 * HN + d];
        Ks[t][d] = base[(size_t)t * 3 * HN + HN + d];
    }
    __syncthreads();
    for (int p = threadIdx.x; p < FN * FN; p += 256) {
        int qi = p / FN, kj = p - qi * FN;
        const float4* qp = (const float4*)&Qs[qi][0];
        const float4* kp = (const float4*)&Ks[kj][0];
        float s = 0.f;
        #pragma unroll
        for (int c = 0; c < DH / 4; ++c) {
            float4 a = qp[c], b = kp[c];
            s += a.x * b.x + a.y * b.y + a.z * b.z + a.w * b.w;
        }
        Ss[qi][kj] = s * 0.0625f;   // 1/sqrt(256)
    }
    __syncthreads();
    if (threadIdx.x < FN) {
        int qi = threadIdx.x;
        float mx = -1e30f;
        for (int j = 0; j < FN; ++j) mx = fmaxf(mx, Ss[qi][j]);
        float sm = 0.f;
        for (int j = 0; j < FN; ++j) { float e = expf(Ss[qi][j] - mx); Ss[qi][j] = e; sm += e; }
        float inv = 1.f / sm;
        for (int j = 0; j < FN; ++j) Ss[qi][j] *= inv;
    }
    __syncthreads();
    // reuse Qs storage for V
    float* Vs = &Qs[0][0];
    for (int i = threadIdx.x; i < FN * DH; i += 256) {
        int t = i >> 8, d = i & 255;
        Vs[t * DH + d] = base[(size_t)t * 3 * HN + 2 * HN + d];
    }
    __syncthreads();
    int d = threadIdx.x;
    float accum = 0.f;
    for (int qi = 0; qi < FN; ++qi) {
        float o = 0.f;
        for (int j = 0; j < FN; ++j) o += Ss[qi][j] * Vs[j * DH + d];
        accum += o;
    }
    obar[(size_t)(b0 + bl) * HN + h * DH + d] = accum * (1.f / (float)FN);
}

// ---------------------------------------------------------------------------
// Fused GRU step: h_out = GRUCell(x, h_in).  Input proj (K=KX) fused with
// recurrent proj (K=HN).  Tile 32 batch x 32 hidden x 3 gates; grid (8,32).
// ---------------------------------------------------------------------------
template<int KX>
__global__ __launch_bounds__(256) void gru_step(const float* __restrict__ x, int xstride,
                                                const float* __restrict__ h_in,
                                                const float* __restrict__ wih,
                                                const float* __restrict__ whh,
                                                const float* __restrict__ bih,
                                                const float* __restrict__ bhh,
                                                float* __restrict__ h_out) {
    const int b0 = blockIdx.x * 32;
    const int j0 = blockIdx.y * 32;
    const int tid = threadIdx.x;
    const int tx = tid & 15;   // hidden sub-tile
    const int ty = tid >> 4;   // batch sub-tile
    float ax[3][2][2] = {{{0.f}}};
    float ah[3][2][2] = {{{0.f}}};
    __shared__ float xs[16][32];       // [k][batch]
    __shared__ float ws[3][16][32];    // [gate][k][hidden]

    // phase 1: x @ wih^T
    for (int k0 = 0; k0 < KX; k0 += 16) {
        #pragma unroll
        for (int r = 0; r < 2; ++r) {
            int e = tid + r * 256;
            int kk = e & 15, bb = e >> 4;
            int k = k0 + kk;
            float v = 0.f;
            if ((KX % 16 == 0) || (k < KX)) v = x[(size_t)(b0 + bb) * xstride + k];
            xs[kk][bb] = v;
        }
        #pragma unroll
        for (int r = 0; r < 6; ++r) {
            int e = tid + r * 256;
            int kk = e & 15, jj = (e >> 4) & 31, g = e >> 9;
            int k = k0 + kk;
            float v = 0.f;
            if ((KX % 16 == 0) || (k < KX)) v = wih[(size_t)(g * HN + j0 + jj) * KX + k];
            ws[g][kk][jj] = v;
        }
        __syncthreads();
        #pragma unroll
        for (int kk = 0; kk < 16; ++kk) {
            float a0 = xs[kk][ty * 2 + 0], a1 = xs[kk][ty * 2 + 1];
            #pragma unroll
            for (int g = 0; g < 3; ++g) {
                float w0 = ws[g][kk][tx * 2 + 0], w1 = ws[g][kk][tx * 2 + 1];
                ax[g][0][0] += a0 * w0; ax[g][0][1] += a0 * w1;
                ax[g][1][0] += a1 * w0; ax[g][1][1] += a1 * w1;
            }
        }
        __syncthreads();
    }
    // phase 2: h @ whh^T (K = HN, exact multiple of 16)
    for (int k0 = 0; k0 < HN; k0 += 16) {
        #pragma unroll
        for (int r = 0; r < 2; ++r) {
            int e = tid + r * 256;
            int kk = e & 15, bb = e >> 4;
            xs[kk][bb] = h_in[(size_t)(b0 + bb) * HN + k0 + kk];
        }
        #pragma unroll
        for (int r = 0; r < 6; ++r) {
            int e = tid + r * 256;
            int kk = e & 15, jj = (e >> 4) & 31, g = e >> 9;
            ws[g][kk][jj] = whh[(size_t)(g * HN + j0 + jj) * HN + k0 + kk];
        }
        __syncthreads();
        #pragma unroll
        for (int kk = 0; kk < 16; ++kk) {
            float a0 = xs[kk][ty * 2 + 0], a1 = xs[kk][ty * 2 + 1];
            #pragma unroll
            for (int g = 0; g < 3; ++g) {
                float w0 = ws[g][kk][tx * 2 + 0], w1 = ws[g][kk][tx * 2 + 1];
                ah[g][0][0] += a0 * w0; ah[g][0][1] += a0 * w1;
                ah[g][1][0] += a1 * w0; ah[g][1][1] += a1 * w1;
            }
        }
        __syncthreads();
    }
    #pragma unroll
    for (int bi = 0; bi < 2; ++bi) {
        int m = b0 + ty * 2 + bi;
        #pragma unroll
        for (int ji = 0; ji < 2; ++ji) {
            int j = j0 + tx * 2 + ji;
            float gir = ax[0][bi][ji] + bih[j];
            float giz = ax[1][bi][ji] + bih[HN + j];
            float gin = ax[2][bi][ji] + bih[2 * HN + j];
            float ghr = ah[0][bi][ji] + bhh[j];
            float ghz = ah[1][bi][ji] + bhh[HN + j];
            float ghn = ah[2][bi][ji] + bhh[2 * HN + j];
            float r = 1.f / (1.f + expf(-(gir + ghr)));
            float z = 1.f / (1.f + expf(-(giz + ghz)));
            float n = tanhf(gin + r * ghn);
            float hp = h_in[(size_t)m * HN + j];
            h_out[(size_t)m * HN + j] = (1.f - z) * n + z * hp;
        }
    }
}

// ---------------------------------------------------------------------------
// Decoder prep: xbuf = poses[:,119]; sixd = mat_to_6d(xbuf)
// mat_to_6d: sixd[j*6+i]   = R[j][i][0]  (i<3, col 0)
//            sixd[j*6+3+i] = R[j][i][1]  (col 1),  R[j][r][c]=x[j*9+r*3+c]
// ---------------------------------------------------------------------------
__global__ __launch_bounds__(128) void prep_kernel(const float* __restrict__ poses,
                                                   float* __restrict__ sixd,
                                                   float* __restrict__ xbuf) {
    int b = blockIdx.x;
    const float* src = poses + ((size_t)b * TT + (TSEED - 1)) * DN;
    for (int d = threadIdx.x; d < DN; d += 128) xbuf[b * DN + d] = src[d];
    for (int p = threadIdx.x; p < JN * 6; p += 128) {
        int j = p / 6, c = p - j * 6;
        int i = (c < 3) ? c : (c - 3);
        int col = (c < 3) ? 0 : 1;
        sixd[b * JN * 6 + p] = src[j * 9 + i * 3 + col];
    }
}

// ---------------------------------------------------------------------------
// spl2: delta[b][j][o] = z1[b][j*128+:128] . w2[j][o][:] + b2[j][o]
//       sixd += delta;  out[b][t][:] = sixd
// ---------------------------------------------------------------------------
__global__ __launch_bounds__(128) void spl2_kernel(const float* __restrict__ z1,
                                                   const float* __restrict__ w2,
                                                   const float* __restrict__ b2,
                                                   float* __restrict__ sixd,
                                                   float* __restrict__ out, int t) {
    int b = blockIdx.x;
    int p = threadIdx.x;
    if (p < JN * 6) {
        int j = p / 6, o = p - j * 6;
        const float* z = z1 + (size_t)b * (JN * 128) + j * 128;
        const float* wv = w2 + (j * 6 + o) * 128;
        float s = b2[j * 6 + o];
        #pragma unroll 4
        for (int k = 0; k < 128; ++k) s += z[k] * wv[k];
        float nv = sixd[b * JN * 6 + p] + s;
        sixd[b * JN * 6 + p] = nv;
        out[((size_t)b * PREDN + t) * (JN * 6) + p] = nv;
    }
}

// ---------------------------------------------------------------------------
// rot6d -> rotmat (interleaved 6d: a1=(v0,v2,v4), a2=(v1,v3,v5));
// xbuf[j*9 + i*3 + c] = b_c[i]  (stack([b1,b2,b3], axis=-1) row-major)
// ---------------------------------------------------------------------------
__global__ __launch_bounds__(256) void rot_kernel(const float* __restrict__ sixd,
                                                  float* __restrict__ xbuf) {
    int i = blockIdx.x * 256 + threadIdx.x;
    if (i >= BB * JN) return;
    int b = i / JN, j = i - b * JN;
    const float* v = sixd + b * JN * 6 + j * 6;
    float a1x = v[0], a1y = v[2], a1z = v[4];
    float a2x = v[1], a2y = v[3], a2z = v[5];
    float n1 = fmaxf(sqrtf(a1x * a1x + a1y * a1y + a1z * a1z), 1e-12f);
    float b1x = a1x / n1, b1y = a1y / n1, b1z = a1z / n1;
    float dt = b1x * a2x + b1y * a2y + b1z * a2z;
    float ox = a2x - dt * b1x, oy = a2y - dt * b1y, oz = a2z - dt * b1z;
    float n2 = fmaxf(sqrtf(ox * ox + oy * oy + oz * oz), 1e-12f);
    float b2x = ox / n2, b2y = oy / n2, b2z = oz / n2;
    float b3x = b1y * b2z - b1z * b2y;
    float b3y = b1z * b2x - b1x * b2z;
    float b3z = b1x * b2y - b1y * b2x;
    float* xr = xbuf + (size_t)b * DN + j * 9;
    xr[0] = b1x; xr[1] = b2x; xr[2] = b3x;
    xr[3] = b1y; xr[4] = b2y; xr[5] = b3y;
    xr[6] = b1z; xr[7] = b2z; xr[8] = b3z;
}

// ---------------------------------------------------------------------------
extern "C" void kernel_launch(void* const* d_in, const int* in_sizes, int n_in,
                              void* d_out, int out_size, void* d_ws, size_t ws_size,
                              hipStream_t stream) {
    const float* poses  = (const float*)d_in[0];
    const float* freq_w = (const float*)d_in[1];
    const float* freq_b = (const float*)d_in[2];
    const float* ain_w  = (const float*)d_in[3];
    const float* ain_b  = (const float*)d_in[4];
    const float* aout_w = (const float*)d_in[5];
    const float* aout_b = (const float*)d_in[6];
    const float* wih0   = (const float*)d_in[7];
    const float* whh0   = (const float*)d_in[8];
    const float* bih0   = (const float*)d_in[9];
    const float* bhh0   = (const float*)d_in[10];
    const float* wih1   = (const float*)d_in[11];
    const float* whh1   = (const float*)d_in[12];
    const float* bih1   = (const float*)d_in[13];
    const float* bhh1   = (const float*)d_in[14];
    const float* pre_w  = (const float*)d_in[15];
    const float* pre_b  = (const float*)d_in[16];
    const float* spl_w1 = (const float*)d_in[17];
    const float* spl_b1 = (const float*)d_in[18];
    const float* spl_w2 = (const float*)d_in[19];
    const float* spl_b2 = (const float*)d_in[20];
    float* out = (float*)d_out;

    // workspace carve (floats); peak ~43 MB
    float* w = (float*)d_ws;
    float* cosm   = w; w += FN * TSEED;
    float* obar   = w; w += BB * HN;
    float* mctx   = w; w += BB * HN;
    float* h0a    = w; w += BB * HN;
    float* h0b    = w; w += BB * HN;
    float* h1a    = w; w += BB * HN;
    float* h1b    = w; w += BB * HN;
    float* hidden = w; w += BB * HN;
    float* z1     = w; w += BB * JN * 128;
    float* sixd   = w; w += BB * JN * 6;
    float* xbuf   = w; w += BB * DN;
    float* freq_c = w; w += RCH * DN;
    float* feat_c = w; w += RCH * HN;
    float* qkv_c  = w; w += RCH * 3 * HN;

    // ---- encoder: DFT -> feat -> qkv -> attention (chunked by 32 batches) ----
    cos_kernel<<<FN, 128, 0, stream>>>(cosm);
    for (int bc = 0; bc < BB / BCH; ++bc) {
        dft_kernel<<<BCH, 256, 0, stream>>>(poses + (size_t)bc * BCH * TT * DN, cosm, freq_c);
        gemm_bt<0, 0><<<dim3((RCH + 63) / 64, HN / 64), 256, 0, stream>>>(
            freq_c, DN, freq_w, DN, freq_b, nullptr, feat_c, RCH, HN, DN);
        gemm_bt<0, 0><<<dim3((RCH + 63) / 64, 3 * HN / 64), 256, 0, stream>>>(
            feat_c, HN, ain_w, HN, ain_b, nullptr, qkv_c, RCH, 3 * HN, HN);
        attn_kernel<<<dim3(BCH, 4), 256, 0, stream>>>(qkv_c, obar, bc * BCH);
    }
    // motion_ctx = mean_t(attn_o) @ aout_w^T + aout_b   (mean commutes with linear)
    gemm_bt<0, 0><<<dim3(BB / 64, HN / 64), 256, 0, stream>>>(
        obar, HN, aout_w, HN, aout_b, nullptr, mctx, BB, HN, HN);

    // ---- GRU encoder: 120 steps, both layers pipelined per step ----
    hipMemsetAsync(h0a, 0, (size_t)BB * HN * sizeof(float), stream);
    hipMemsetAsync(h1a, 0, (size_t)BB * HN * sizeof(float), stream);
    float *h0c = h0a, *h0n = h0b, *h1c = h1a, *h1n = h1b;
    dim3 ggrid(BB / 32, HN / 32);
    for (int t = 0; t < TSEED; ++t) {
        gru_step<DN><<<ggrid, 256, 0, stream>>>(poses + (size_t)t * DN, TT * DN,
                                                h0c, wih0, whh0, bih0, bhh0, h0n);
        gru_step<HN><<<ggrid, 256, 0, stream>>>(h0n, HN, h1c, wih1, whh1, bih1, bhh1, h1n);
        float* tmp;
        tmp = h0c; h0c = h0n; h0n = tmp;
        tmp = h1c; h1c = h1n; h1n = tmp;
    }

    // ---- autoregressive decoder: 24 steps ----
    prep_kernel<<<BB, 128, 0, stream>>>(poses, sixd, xbuf);
    for (int t = 0; t < PREDN; ++t) {
        gru_step<DN><<<ggrid, 256, 0, stream>>>(xbuf, DN, h0c, wih0, whh0, bih0, bhh0, h0n);
        gru_step<HN><<<ggrid, 256, 0, stream>>>(h0n, HN, h1c, wih1, whh1, bih1, bhh1, h1n);
        // hidden = relu(h1 @ pre_w^T + pre_b) + motion_ctx
        gemm_bt<1, 1><<<dim3(BB / 64, HN / 64), 256, 0, stream>>>(
            h1n, HN, pre_w, HN, pre_b, mctx, hidden, BB, HN, HN);
        // z1 = relu(hidden @ spl_w1^T + spl_b1)   (spl_w1 flat: (1920,1024))
        gemm_bt<1, 0><<<dim3(BB / 64, (JN * 128) / 64), 256, 0, stream>>>(
            hidden, HN, spl_w1, HN, spl_b1, nullptr, z1, BB, JN * 128, HN);
        spl2_kernel<<<BB, 128, 0, stream>>>(z1, spl_w2, spl_b2, sixd, out, t);
        rot_kernel<<<(BB * JN + 255) / 256, 256, 0, stream>>>(sixd, xbuf);
        float* tmp;
        tmp = h0c; h0c = h0n; h0n = tmp;
        tmp = h1c; h1c = h1n; h1n = tmp;
    }
}

// Round 3
// 28650.238 us; speedup vs baseline: 1.6932x; 1.6932x over previous
//
#include <hip/hip_runtime.h>

#define BB     256
#define TSEED  120
#define PREDN  24
#define JN     15
#define HN     1024
#define DN     135
#define FN     61
#define TT     144
#define DH     256
#define BCH    32
#define RCH    (BCH*FN)   // 1952 rows per encoder chunk
#define KPF    160        // 135 padded for freq weights
#define KP0    1184       // 135+1024 padded to 37*32
#define KP1    2048

typedef __attribute__((ext_vector_type(8))) short short8v;
typedef __attribute__((ext_vector_type(4))) float f32x4;

__device__ __forceinline__ short f2b(float f) {
    union { float f; unsigned u; } v; v.f = f;
    unsigned r = (v.u + 0x7FFFu + ((v.u >> 16) & 1u)) >> 16;
    return (short)r;
}
__device__ __forceinline__ float b2f(short h) {
    union { unsigned u; float f; } x; x.u = ((unsigned)(unsigned short)h) << 16; return x.f;
}
__device__ __forceinline__ void fsplit(float v, short& h, short& l) {
    h = f2b(v); l = f2b(v - b2f(h));
}

// ---------------------------------------------------------------------------
// prepack: GRU fused weight  W'[4096][KP] = [Wr|Ur ; Wz|Uz ; Wn|0 ; 0|Un]
// stored as bf16 hi/lo pair
// ---------------------------------------------------------------------------
__global__ __launch_bounds__(256) void pack_gruw(const float* __restrict__ wih,
                                                 const float* __restrict__ whh,
                                                 int KX, int KP,
                                                 short* __restrict__ Wh,
                                                 short* __restrict__ Wl) {
    int n = blockIdx.x, g = n >> 10, j = n & 1023;
    for (int k = threadIdx.x; k < KP; k += 256) {
        float v = 0.f;
        if (k < KX) {
            if (g < 3) v = wih[(size_t)(g * HN + j) * KX + k];
        } else if (k < KX + HN) {
            int kk = k - KX;
            if (g == 0)      v = whh[(size_t)j * HN + kk];
            else if (g == 1) v = whh[(size_t)(HN + j) * HN + kk];
            else if (g == 3) v = whh[(size_t)(2 * HN + j) * HN + kk];
        }
        short hh, ll; fsplit(v, hh, ll);
        Wh[(size_t)n * KP + k] = hh;
        Wl[(size_t)n * KP + k] = ll;
    }
}

__global__ __launch_bounds__(256) void pack_grub(const float* __restrict__ bih,
                                                 const float* __restrict__ bhh,
                                                 float* __restrict__ bp) {
    int n = blockIdx.x * 256 + threadIdx.x;
    if (n < 4 * HN) {
        int g = n >> 10, j = n & 1023;
        float v;
        if (g == 0)      v = bih[j] + bhh[j];
        else if (g == 1) v = bih[HN + j] + bhh[HN + j];
        else if (g == 2) v = bih[2 * HN + j];
        else             v = bhh[2 * HN + j];
        bp[n] = v;
    }
}

// cast fp32 [N][K] -> bf16 pair [N][KP] zero-padded
__global__ __launch_bounds__(256) void castw(const float* __restrict__ w,
                                             short* __restrict__ oh,
                                             short* __restrict__ ol, int K, int KP) {
    int n = blockIdx.x;
    for (int k = threadIdx.x; k < KP; k += 256) {
        float v = (k < K) ? w[(size_t)n * K + k] : 0.f;
        short hh, ll; fsplit(v, hh, ll);
        oh[(size_t)n * KP + k] = hh;
        ol[(size_t)n * KP + k] = ll;
    }
}

// ---------------------------------------------------------------------------
// cos table + DFT (real part of rfft)
// ---------------------------------------------------------------------------
__global__ __launch_bounds__(128) void cos_kernel(float* __restrict__ cosm) {
    int f = blockIdx.x, t = threadIdx.x;
    if (t < TSEED) {
        int ft = (f * t) % TSEED;
        cosm[f * TSEED + t] = cosf((float)ft * (6.283185307179586f / (float)TSEED));
    }
}

__global__ __launch_bounds__(256) void dft_kernel(const float* __restrict__ poses,
                                                  const float* __restrict__ cosm,
                                                  float* __restrict__ freq) {
    __shared__ float cs[FN * TSEED];
    for (int i = threadIdx.x; i < FN * TSEED; i += 256) cs[i] = cosm[i];
    __syncthreads();
    const float* xp = poses + (size_t)blockIdx.x * TT * DN;
    float* fp = freq + (size_t)blockIdx.x * FN * DN;
    for (int o = threadIdx.x; o < FN * DN; o += 256) {
        int f = o / DN, d = o - f * DN;
        const float* cf = &cs[f * TSEED];
        float s = 0.f;
        #pragma unroll 4
        for (int t = 0; t < TSEED; ++t) s += xp[t * DN + d] * cf[t];
        fp[o] = s;
    }
}

// ---------------------------------------------------------------------------
// Split-bf16 MFMA GEMM: C = EPI(A @ B^T + bias), A/B ~ hi+lo bf16 pairs.
// acc += Ah*Bh + Ah*Bl + Al*Bh  (3 MFMAs, ~fp32-class precision)
// A = [A0 f32 (split on the fly) | A1 pair | A2 pair | 0]; B pair [N][KP].
// Tile 32x64, 256 threads (4 waves).  M%32==0, N%64==0.
// EPI: 0 bias->f32 | 1 bias->pair | 2 relu(v+bias)+addm->pair | 3 relu->f32
// ---------------------------------------------------------------------------
template<int EPI>
__global__ __launch_bounds__(256) void mgemm(
        const float* __restrict__ A0, int a0w, int a0s,
        const short* __restrict__ A1h, const short* __restrict__ A1l, int a1w, int a1s,
        const short* __restrict__ A2h, const short* __restrict__ A2l, int a2w, int a2s,
        const short* __restrict__ Bh, const short* __restrict__ Bl, int KP,
        const float* __restrict__ bias, const float* __restrict__ addm,
        float* __restrict__ Cf, short* __restrict__ Cbh, short* __restrict__ Cbl,
        int N) {
    __shared__ short Ash[32][40];
    __shared__ short Asl[32][40];
    __shared__ short Bsh[64][40];
    __shared__ short Bsl[64][40];
    const int tid = threadIdx.x;
    const int m0 = blockIdx.x * 32, n0 = blockIdx.y * 64;
    const int ra = tid >> 3, ka = (tid & 7) * 4;
    const int rb = tid >> 2, kb = (tid & 3) * 8;
    const int lane = tid & 63, wv = tid >> 6;
    const int wm = (wv & 1) * 16, wn = (wv >> 1) * 32;
    const int fr = lane & 15, fo = (lane >> 4) * 8;
    const int a01 = a0w + a1w, a012 = a01 + a2w;
    f32x4 acc0 = {0.f, 0.f, 0.f, 0.f}, acc1 = {0.f, 0.f, 0.f, 0.f};

    auto ldA = [&](int k, short& hh, short& ll) {
        if (k < a0w) {
            fsplit(A0[(size_t)(m0 + ra) * a0s + k], hh, ll);
        } else if (k < a01) {
            size_t o = (size_t)(m0 + ra) * a1s + (k - a0w);
            hh = A1h[o]; ll = A1l[o];
        } else if (k < a012) {
            size_t o = (size_t)(m0 + ra) * a2s + (k - a01);
            hh = A2h[o]; ll = A2l[o];
        } else { hh = 0; ll = 0; }
    };

    short avh[4], avl[4];
    short8v bvh, bvl;
    #pragma unroll
    for (int j = 0; j < 4; ++j) ldA(ka + j, avh[j], avl[j]);
    bvh = *(const short8v*)(Bh + (size_t)(n0 + rb) * KP + kb);
    bvl = *(const short8v*)(Bl + (size_t)(n0 + rb) * KP + kb);

    for (int k0 = 0; k0 < KP; k0 += 32) {
        #pragma unroll
        for (int j = 0; j < 4; ++j) { Ash[ra][ka + j] = avh[j]; Asl[ra][ka + j] = avl[j]; }
        *(short8v*)&Bsh[rb][kb] = bvh;
        *(short8v*)&Bsl[rb][kb] = bvl;
        int kn = k0 + 32;
        if (kn < KP) {
            #pragma unroll
            for (int j = 0; j < 4; ++j) ldA(kn + ka + j, avh[j], avl[j]);
            bvh = *(const short8v*)(Bh + (size_t)(n0 + rb) * KP + kn + kb);
            bvl = *(const short8v*)(Bl + (size_t)(n0 + rb) * KP + kn + kb);
        }
        __syncthreads();
        short8v ah  = *(const short8v*)&Ash[wm + fr][fo];
        short8v al  = *(const short8v*)&Asl[wm + fr][fo];
        short8v b0h = *(const short8v*)&Bsh[wn + fr][fo];
        short8v b0l = *(const short8v*)&Bsl[wn + fr][fo];
        short8v b1h = *(const short8v*)&Bsh[wn + 16 + fr][fo];
        short8v b1l = *(const short8v*)&Bsl[wn + 16 + fr][fo];
        acc0 = __builtin_amdgcn_mfma_f32_16x16x32_bf16(ah, b0h, acc0, 0, 0, 0);
        acc0 = __builtin_amdgcn_mfma_f32_16x16x32_bf16(ah, b0l, acc0, 0, 0, 0);
        acc0 = __builtin_amdgcn_mfma_f32_16x16x32_bf16(al, b0h, acc0, 0, 0, 0);
        acc1 = __builtin_amdgcn_mfma_f32_16x16x32_bf16(ah, b1h, acc1, 0, 0, 0);
        acc1 = __builtin_amdgcn_mfma_f32_16x16x32_bf16(ah, b1l, acc1, 0, 0, 0);
        acc1 = __builtin_amdgcn_mfma_f32_16x16x32_bf16(al, b1h, acc1, 0, 0, 0);
        __syncthreads();
    }

    const int rq = (lane >> 4) * 4;
    #pragma unroll
    for (int f = 0; f < 2; ++f) {
        f32x4 acc = f ? acc1 : acc0;
        int n = n0 + wn + f * 16 + fr;
        float bb = bias[n];
        #pragma unroll
        for (int q = 0; q < 4; ++q) {
            int m = m0 + wm + rq + q;
            size_t off = (size_t)m * N + n;
            float v = acc[q] + bb;
            if (EPI == 0) {
                Cf[off] = v;
            } else if (EPI == 1) {
                short hh, ll; fsplit(v, hh, ll);
                Cbh[off] = hh; Cbl[off] = ll;
            } else if (EPI == 2) {
                v = fmaxf(v, 0.f) + addm[off];
                short hh, ll; fsplit(v, hh, ll);
                Cbh[off] = hh; Cbl[off] = ll;
            } else {
                Cf[off] = fmaxf(v, 0.f);
            }
        }
    }
}

// ---------------------------------------------------------------------------
// GRU pointwise combine: gates G[b][4096] = [R|Z|NI|NH]; h updated in place,
// hi/lo mirror written for the next GEMM.
// ---------------------------------------------------------------------------
__global__ __launch_bounds__(1024) void gru_comb(const float* __restrict__ G,
                                                 float* __restrict__ h,
                                                 short* __restrict__ hh_,
                                                 short* __restrict__ hl_) {
    int b = blockIdx.x, j = threadIdx.x;
    const float* g = G + (size_t)b * 4096;
    float r = 1.f / (1.f + expf(-g[j]));
    float z = 1.f / (1.f + expf(-g[HN + j]));
    float n = tanhf(g[2 * HN + j] + r * g[3 * HN + j]);
    size_t off = (size_t)b * HN + j;
    float hn = (1.f - z) * n + z * h[off];
    h[off] = hn;
    short hh, ll; fsplit(hn, hh, ll);
    hh_[off] = hh; hl_[off] = ll;
}

// ---------------------------------------------------------------------------
// attention (one block per (batch, head)); accumulates mean_t(o) into obar
// ---------------------------------------------------------------------------
__global__ __launch_bounds__(256) void attn_kernel(const float* __restrict__ qkv,
                                                   float* __restrict__ obar, int b0) {
    __shared__ float Qs[FN][DH];
    __shared__ float Ks[FN][DH];
    __shared__ float Ss[FN][62];
    const int bl = blockIdx.x, h = blockIdx.y;
    const float* base = qkv + (size_t)bl * FN * 3 * HN + h * DH;
    for (int i = threadIdx.x; i < FN * DH; i += 256) {
        int t = i >> 8, d = i & 255;
        Qs[t][d] = base[(size_t)t * 3 * HN + d];
        Ks[t][d] = base[(size_t)t * 3 * HN + HN + d];
    }
    __syncthreads();
    for (int p = threadIdx.x; p < FN * FN; p += 256) {
        int qi = p / FN, kj = p - qi * FN;
        const float4* qp = (const float4*)&Qs[qi][0];
        const float4* kp = (const float4*)&Ks[kj][0];
        float s = 0.f;
        #pragma unroll
        for (int c = 0; c < DH / 4; ++c) {
            float4 a = qp[c], b = kp[c];
            s += a.x * b.x + a.y * b.y + a.z * b.z + a.w * b.w;
        }
        Ss[qi][kj] = s * 0.0625f;
    }
    __syncthreads();
    if (threadIdx.x < FN) {
        int qi = threadIdx.x;
        float mx = -1e30f;
        for (int j = 0; j < FN; ++j) mx = fmaxf(mx, Ss[qi][j]);
        float sm = 0.f;
        for (int j = 0; j < FN; ++j) { float e = expf(Ss[qi][j] - mx); Ss[qi][j] = e; sm += e; }
        float inv = 1.f / sm;
        for (int j = 0; j < FN; ++j) Ss[qi][j] *= inv;
    }
    __syncthreads();
    float* Vs = &Qs[0][0];
    for (int i = threadIdx.x; i < FN * DH; i += 256) {
        int t = i >> 8, d = i & 255;
        Vs[t * DH + d] = base[(size_t)t * 3 * HN + 2 * HN + d];
    }
    __syncthreads();
    int d = threadIdx.x;
    float accum = 0.f;
    for (int qi = 0; qi < FN; ++qi) {
        float o = 0.f;
        for (int j = 0; j < FN; ++j) o += Ss[qi][j] * Vs[j * DH + d];
        accum += o;
    }
    obar[(size_t)(b0 + bl) * HN + h * DH + d] = accum * (1.f / (float)FN);
}

// ---------------------------------------------------------------------------
// decoder prep / spl2 / rot6d
// ---------------------------------------------------------------------------
__global__ __launch_bounds__(128) void prep_kernel(const float* __restrict__ poses,
                                                   float* __restrict__ sixd,
                                                   float* __restrict__ xbuf) {
    int b = blockIdx.x;
    const float* src = poses + ((size_t)b * TT + (TSEED - 1)) * DN;
    for (int d = threadIdx.x; d < DN; d += 128) xbuf[b * DN + d] = src[d];
    for (int p = threadIdx.x; p < JN * 6; p += 128) {
        int j = p / 6, c = p - j * 6;
        int i = (c < 3) ? c : (c - 3);
        int col = (c < 3) ? 0 : 1;
        sixd[b * JN * 6 + p] = src[j * 9 + i * 3 + col];
    }
}

__global__ __launch_bounds__(128) void spl2_kernel(const float* __restrict__ z1,
                                                   const float* __restrict__ w2,
                                                   const float* __restrict__ b2,
                                                   float* __restrict__ sixd,
                                                   float* __restrict__ out, int t) {
    int b = blockIdx.x, p = threadIdx.x;
    if (p < JN * 6) {
        int j = p / 6, o = p - j * 6;
        const float* z = z1 + (size_t)b * (JN * 128) + j * 128;
        const float* wv = w2 + (j * 6 + o) * 128;
        float s = b2[j * 6 + o];
        #pragma unroll 4
        for (int k = 0; k < 128; ++k) s += z[k] * wv[k];
        float nv = sixd[b * JN * 6 + p] + s;
        sixd[b * JN * 6 + p] = nv;
        out[((size_t)b * PREDN + t) * (JN * 6) + p] = nv;
    }
}

__global__ __launch_bounds__(256) void rot_kernel(const float* __restrict__ sixd,
                                                  float* __restrict__ xbuf) {
    int i = blockIdx.x * 256 + threadIdx.x;
    if (i >= BB * JN) return;
    int b = i / JN, j = i - b * JN;
    const float* v = sixd + b * JN * 6 + j * 6;
    float a1x = v[0], a1y = v[2], a1z = v[4];
    float a2x = v[1], a2y = v[3], a2z = v[5];
    float n1 = fmaxf(sqrtf(a1x * a1x + a1y * a1y + a1z * a1z), 1e-12f);
    float b1x = a1x / n1, b1y = a1y / n1, b1z = a1z / n1;
    float dt = b1x * a2x + b1y * a2y + b1z * a2z;
    float ox = a2x - dt * b1x, oy = a2y - dt * b1y, oz = a2z - dt * b1z;
    float n2 = fmaxf(sqrtf(ox * ox + oy * oy + oz * oz), 1e-12f);
    float b2x = ox / n2, b2y = oy / n2, b2z = oz / n2;
    float b3x = b1y * b2z - b1z * b2y;
    float b3y = b1z * b2x - b1x * b2z;
    float b3z = b1x * b2y - b1y * b2x;
    float* xr = xbuf + (size_t)b * DN + j * 9;
    xr[0] = b1x; xr[1] = b2x; xr[2] = b3x;
    xr[3] = b1y; xr[4] = b2y; xr[5] = b3y;
    xr[6] = b1z; xr[7] = b2z; xr[8] = b3z;
}

// ---------------------------------------------------------------------------
extern "C" void kernel_launch(void* const* d_in, const int* in_sizes, int n_in,
                              void* d_out, int out_size, void* d_ws, size_t ws_size,
                              hipStream_t stream) {
    const float* poses  = (const float*)d_in[0];
    const float* freq_w = (const float*)d_in[1];
    const float* freq_b = (const float*)d_in[2];
    const float* ain_w  = (const float*)d_in[3];
    const float* ain_b  = (const float*)d_in[4];
    const float* aout_w = (const float*)d_in[5];
    const float* aout_b = (const float*)d_in[6];
    const float* wih0   = (const float*)d_in[7];
    const float* whh0   = (const float*)d_in[8];
    const float* bih0   = (const float*)d_in[9];
    const float* bhh0   = (const float*)d_in[10];
    const float* wih1   = (const float*)d_in[11];
    const float* whh1   = (const float*)d_in[12];
    const float* bih1   = (const float*)d_in[13];
    const float* bhh1   = (const float*)d_in[14];
    const float* pre_w  = (const float*)d_in[15];
    const float* pre_b  = (const float*)d_in[16];
    const float* spl_w1 = (const float*)d_in[17];
    const float* spl_b1 = (const float*)d_in[18];
    const float* spl_w2 = (const float*)d_in[19];
    const float* spl_b2 = (const float*)d_in[20];
    float* out = (float*)d_out;

    char* p = (char*)d_ws;
    auto alloc = [&](size_t bytes) { void* r = p; p += (bytes + 255) & ~(size_t)255; return r; };
    short* W0h    = (short*)alloc((size_t)4096 * KP0 * 2);
    short* W0l    = (short*)alloc((size_t)4096 * KP0 * 2);
    short* W1h    = (short*)alloc((size_t)4096 * KP1 * 2);
    short* W1l    = (short*)alloc((size_t)4096 * KP1 * 2);
    float* b0p    = (float*)alloc(4096 * 4);
    float* b1p    = (float*)alloc(4096 * 4);
    short* freqh  = (short*)alloc((size_t)1024 * KPF * 2);
    short* freql  = (short*)alloc((size_t)1024 * KPF * 2);
    short* ainh   = (short*)alloc((size_t)3072 * 1024 * 2);
    short* ainl   = (short*)alloc((size_t)3072 * 1024 * 2);
    short* aouth  = (short*)alloc((size_t)1024 * 1024 * 2);
    short* aoutl  = (short*)alloc((size_t)1024 * 1024 * 2);
    short* preh   = (short*)alloc((size_t)1024 * 1024 * 2);
    short* prel   = (short*)alloc((size_t)1024 * 1024 * 2);
    short* spl1h  = (short*)alloc((size_t)1920 * 1024 * 2);
    short* spl1l  = (short*)alloc((size_t)1920 * 1024 * 2);
    float* cosm   = (float*)alloc(FN * TSEED * 4);
    float* freqf  = (float*)alloc((size_t)BB * FN * DN * 4);
    short* feath  = (short*)alloc((size_t)RCH * HN * 2);
    short* featl  = (short*)alloc((size_t)RCH * HN * 2);
    float* qkvc   = (float*)alloc((size_t)RCH * 3 * HN * 4);
    float* obar   = (float*)alloc((size_t)BB * HN * 4);
    float* mctx   = (float*)alloc((size_t)BB * HN * 4);
    float* G      = (float*)alloc((size_t)BB * 4096 * 4);
    float* h0     = (float*)alloc((size_t)BB * HN * 4);
    float* h1     = (float*)alloc((size_t)BB * HN * 4);
    short* h0h    = (short*)alloc((size_t)BB * HN * 2);
    short* h0l    = (short*)alloc((size_t)BB * HN * 2);
    short* h1h    = (short*)alloc((size_t)BB * HN * 2);
    short* h1l    = (short*)alloc((size_t)BB * HN * 2);
    short* hidh   = (short*)alloc((size_t)BB * HN * 2);
    short* hidl   = (short*)alloc((size_t)BB * HN * 2);
    float* z1     = (float*)alloc((size_t)BB * JN * 128 * 4);
    float* sixd   = (float*)alloc((size_t)BB * JN * 6 * 4);
    float* xbuf   = (float*)alloc((size_t)BB * DN * 4);

    // ---- prepack (every call; graph-safe) ----
    pack_gruw<<<4096, 256, 0, stream>>>(wih0, whh0, DN, KP0, W0h, W0l);
    pack_gruw<<<4096, 256, 0, stream>>>(wih1, whh1, HN, KP1, W1h, W1l);
    pack_grub<<<16, 256, 0, stream>>>(bih0, bhh0, b0p);
    pack_grub<<<16, 256, 0, stream>>>(bih1, bhh1, b1p);
    castw<<<1024, 256, 0, stream>>>(freq_w, freqh, freql, DN, KPF);
    castw<<<3072, 256, 0, stream>>>(ain_w, ainh, ainl, HN, HN);
    castw<<<1024, 256, 0, stream>>>(aout_w, aouth, aoutl, HN, HN);
    castw<<<1024, 256, 0, stream>>>(pre_w, preh, prel, HN, HN);
    castw<<<1920, 256, 0, stream>>>(spl_w1, spl1h, spl1l, HN, HN);

    // ---- encoder ----
    cos_kernel<<<FN, 128, 0, stream>>>(cosm);
    dft_kernel<<<BB, 256, 0, stream>>>(poses, cosm, freqf);
    for (int bc = 0; bc < BB / BCH; ++bc) {
        mgemm<1><<<dim3(RCH / 32, HN / 64), 256, 0, stream>>>(
            freqf + (size_t)bc * RCH * DN, DN, DN,
            nullptr, nullptr, 0, 0, nullptr, nullptr, 0, 0,
            freqh, freql, KPF, freq_b, nullptr, nullptr, feath, featl, HN);
        mgemm<0><<<dim3(RCH / 32, 3 * HN / 64), 256, 0, stream>>>(
            nullptr, 0, 0, feath, featl, HN, HN, nullptr, nullptr, 0, 0,
            ainh, ainl, HN, ain_b, nullptr, qkvc, nullptr, nullptr, 3 * HN);
        attn_kernel<<<dim3(BCH, 4), 256, 0, stream>>>(qkvc, obar, bc * BCH);
    }
    mgemm<0><<<dim3(BB / 32, HN / 64), 256, 0, stream>>>(
        obar, HN, HN, nullptr, nullptr, 0, 0, nullptr, nullptr, 0, 0,
        aouth, aoutl, HN, aout_b, nullptr, mctx, nullptr, nullptr, HN);

    // ---- GRU encoder ----
    hipMemsetAsync(h0, 0, (size_t)BB * HN * 4, stream);
    hipMemsetAsync(h1, 0, (size_t)BB * HN * 4, stream);
    hipMemsetAsync(h0h, 0, (size_t)BB * HN * 2, stream);
    hipMemsetAsync(h0l, 0, (size_t)BB * HN * 2, stream);
    hipMemsetAsync(h1h, 0, (size_t)BB * HN * 2, stream);
    hipMemsetAsync(h1l, 0, (size_t)BB * HN * 2, stream);
    dim3 ggrid(BB / 32, 4096 / 64);
    for (int t = 0; t < TSEED; ++t) {
        mgemm<0><<<ggrid, 256, 0, stream>>>(
            poses + (size_t)t * DN, DN, TT * DN,
            h0h, h0l, HN, HN, nullptr, nullptr, 0, 0,
            W0h, W0l, KP0, b0p, nullptr, G, nullptr, nullptr, 4096);
        gru_comb<<<BB, 1024, 0, stream>>>(G, h0, h0h, h0l);
        mgemm<0><<<ggrid, 256, 0, stream>>>(
            nullptr, 0, 0, h0h, h0l, HN, HN, h1h, h1l, HN, HN,
            W1h, W1l, KP1, b1p, nullptr, G, nullptr, nullptr, 4096);
        gru_comb<<<BB, 1024, 0, stream>>>(G, h1, h1h, h1l);
    }

    // ---- decoder ----
    prep_kernel<<<BB, 128, 0, stream>>>(poses, sixd, xbuf);
    for (int t = 0; t < PREDN; ++t) {
        mgemm<0><<<ggrid, 256, 0, stream>>>(
            xbuf, DN, DN, h0h, h0l, HN, HN, nullptr, nullptr, 0, 0,
            W0h, W0l, KP0, b0p, nullptr, G, nullptr, nullptr, 4096);
        gru_comb<<<BB, 1024, 0, stream>>>(G, h0, h0h, h0l);
        mgemm<0><<<ggrid, 256, 0, stream>>>(
            nullptr, 0, 0, h0h, h0l, HN, HN, h1h, h1l, HN, HN,
            W1h, W1l, KP1, b1p, nullptr, G, nullptr, nullptr, 4096);
        gru_comb<<<BB, 1024, 0, stream>>>(G, h1, h1h, h1l);
        mgemm<2><<<dim3(BB / 32, HN / 64), 256, 0, stream>>>(
            nullptr, 0, 0, h1h, h1l, HN, HN, nullptr, nullptr, 0, 0,
            preh, prel, HN, pre_b, mctx, nullptr, hidh, hidl, HN);
        mgemm<3><<<dim3(BB / 32, 1920 / 64), 256, 0, stream>>>(
            nullptr, 0, 0, hidh, hidl, HN, HN, nullptr, nullptr, 0, 0,
            spl1h, spl1l, HN, spl_b1, nullptr, z1, nullptr, nullptr, 1920);
        spl2_kernel<<<BB, 128, 0, stream>>>(z1, spl_w2, spl_b2, sixd, out, t);
        rot_kernel<<<(BB * JN + 255) / 256, 256, 0, stream>>>(sixd, xbuf);
    }
}

// Round 4
// 13999.501 us; speedup vs baseline: 3.4651x; 2.0465x over previous
//
#include <hip/hip_runtime.h>

#define BB     256
#define TSEED  120
#define PREDN  24
#define JN     15
#define HN     1024
#define DN     135
#define FN     61
#define TT     144
#define DH     256
#define BCH    32
#define RCH    (BCH*FN)   // 1952 rows per encoder chunk
#define KPF    160        // 135 padded for freq weights
#define XWP    160        // padded x width for GRU layer0
#define KP0    (XWP+HN)   // 1184
#define KP1    (2*HN)     // 2048
#define KS     4          // K-split for GRU GEMM

typedef __attribute__((ext_vector_type(8))) short short8v;
typedef __attribute__((ext_vector_type(4))) float f32x4;

__device__ __forceinline__ short f2b(float f) {
    union { float f; unsigned u; } v; v.f = f;
    unsigned r = (v.u + 0x7FFFu + ((v.u >> 16) & 1u)) >> 16;
    return (short)r;
}
__device__ __forceinline__ float b2f(short h) {
    union { unsigned u; float f; } x; x.u = ((unsigned)(unsigned short)h) << 16; return x.f;
}
__device__ __forceinline__ void fsplit(float v, short& h, short& l) {
    h = f2b(v); l = f2b(v - b2f(h));
}

// ---------------------------------------------------------------------------
// prepack: GRU fused weight  W'[4096][KP] = [Wr|pad|Ur ; Wz|pad|Uz ; Wn|pad|0 ; 0|pad|Un]
// x-part occupies [0,KX), zero pad to XW, recurrent part [XW, XW+HN).
// ---------------------------------------------------------------------------
__global__ __launch_bounds__(256) void pack_gruw(const float* __restrict__ wih,
                                                 const float* __restrict__ whh,
                                                 int KX, int XW, int KP,
                                                 short* __restrict__ Wh,
                                                 short* __restrict__ Wl) {
    int n = blockIdx.x, g = n >> 10, j = n & 1023;
    for (int k = threadIdx.x; k < KP; k += 256) {
        float v = 0.f;
        if (k < KX) {
            if (g < 3) v = wih[(size_t)(g * HN + j) * KX + k];
        } else if (k >= XW && k < XW + HN) {
            int kk = k - XW;
            if (g == 0)      v = whh[(size_t)j * HN + kk];
            else if (g == 1) v = whh[(size_t)(HN + j) * HN + kk];
            else if (g == 3) v = whh[(size_t)(2 * HN + j) * HN + kk];
        }
        short hh, ll; fsplit(v, hh, ll);
        Wh[(size_t)n * KP + k] = hh;
        Wl[(size_t)n * KP + k] = ll;
    }
}

__global__ __launch_bounds__(256) void pack_grub(const float* __restrict__ bih,
                                                 const float* __restrict__ bhh,
                                                 float* __restrict__ bp) {
    int n = blockIdx.x * 256 + threadIdx.x;
    if (n < 4 * HN) {
        int g = n >> 10, j = n & 1023;
        float v;
        if (g == 0)      v = bih[j] + bhh[j];
        else if (g == 1) v = bih[HN + j] + bhh[HN + j];
        else if (g == 2) v = bih[2 * HN + j];
        else             v = bhh[2 * HN + j];
        bp[n] = v;
    }
}

// cast fp32 [N][K] -> bf16 pair [N][KP] zero-padded
__global__ __launch_bounds__(256) void castw(const float* __restrict__ w,
                                             short* __restrict__ oh,
                                             short* __restrict__ ol, int K, int KP) {
    int n = blockIdx.x;
    for (int k = threadIdx.x; k < KP; k += 256) {
        float v = (k < K) ? w[(size_t)n * K + k] : 0.f;
        short hh, ll; fsplit(v, hh, ll);
        oh[(size_t)n * KP + k] = hh;
        ol[(size_t)n * KP + k] = ll;
    }
}

// pack poses[:, t, :] -> X pair [t][256][XWP] (pad 135->160 zero)
__global__ __launch_bounds__(256) void pack_x(const float* __restrict__ poses,
                                              short* __restrict__ Xh,
                                              short* __restrict__ Xl) {
    int t = blockIdx.x;
    short* oh = Xh + (size_t)t * BB * XWP;
    short* ol = Xl + (size_t)t * BB * XWP;
    for (int i = threadIdx.x; i < BB * XWP; i += 256) {
        int b = i / XWP, k = i - b * XWP;
        float v = (k < DN) ? poses[((size_t)b * TT + t) * DN + k] : 0.f;
        short hh, ll; fsplit(v, hh, ll);
        oh[i] = hh; ol[i] = ll;
    }
}

// ---------------------------------------------------------------------------
// cos table + DFT (real part of rfft)
// ---------------------------------------------------------------------------
__global__ __launch_bounds__(128) void cos_kernel(float* __restrict__ cosm) {
    int f = blockIdx.x, t = threadIdx.x;
    if (t < TSEED) {
        int ft = (f * t) % TSEED;
        cosm[f * TSEED + t] = cosf((float)ft * (6.283185307179586f / (float)TSEED));
    }
}

__global__ __launch_bounds__(256) void dft_kernel(const float* __restrict__ poses,
                                                  const float* __restrict__ cosm,
                                                  float* __restrict__ freq) {
    __shared__ float cs[FN * TSEED];
    for (int i = threadIdx.x; i < FN * TSEED; i += 256) cs[i] = cosm[i];
    __syncthreads();
    const float* xp = poses + (size_t)blockIdx.x * TT * DN;
    float* fp = freq + (size_t)blockIdx.x * FN * DN;
    for (int o = threadIdx.x; o < FN * DN; o += 256) {
        int f = o / DN, d = o - f * DN;
        const float* cf = &cs[f * TSEED];
        float s = 0.f;
        #pragma unroll 4
        for (int t = 0; t < TSEED; ++t) s += xp[t * DN + d] * cf[t];
        fp[o] = s;
    }
}

// ---------------------------------------------------------------------------
// GRU GEMM: G[ks][256][4096] partial = A @ W^T over this block's K-chunk range.
// A = [seg1 pair (w1, stride s1) | seg2 pair (stride s2)], both widths %32==0.
// BM=256 (whole batch) x BN=32, 512 threads (8 waves), K-split across ks.
// Weight bytes are read exactly ONCE per GEMM (no M-block redundancy).
// LDS layout [kgroup][row][8] -> 16B-aligned b128 ops, ~2-way banking.
// ---------------------------------------------------------------------------
__global__ __launch_bounds__(512) void ggemm(
        const short* __restrict__ A1h, const short* __restrict__ A1l, int w1, int s1,
        const short* __restrict__ A2h, const short* __restrict__ A2l, int s2,
        const short* __restrict__ Wh, const short* __restrict__ Wl, int KP, int NCH,
        float* __restrict__ Gout) {
    __shared__ short Ash[4][257][8];
    __shared__ short Asl[4][257][8];
    __shared__ short Bsh[4][33][8];
    __shared__ short Bsl[4][33][8];
    const int tid = threadIdx.x;
    const int ks = blockIdx.x, by = blockIdx.y;
    const int n0 = by * 32;
    const int c0 = (NCH * ks) / KS, c1 = (NCH * (ks + 1)) / KS;
    const int lane = tid & 63, wv = tid >> 6;
    const int fr = lane & 15, kg = lane >> 4;
    const int rq = kg * 4;
    const int ar = tid >> 2, akg = tid & 3;           // A loader: rows ar, ar+128
    const int br = (tid & 127) >> 2, bkg = tid & 3;   // B loader (tid<256)
    f32x4 acc[2][2];
    acc[0][0] = (f32x4){0.f,0.f,0.f,0.f}; acc[0][1] = (f32x4){0.f,0.f,0.f,0.f};
    acc[1][0] = (f32x4){0.f,0.f,0.f,0.f}; acc[1][1] = (f32x4){0.f,0.f,0.f,0.f};

    short8v rA0h, rA0l, rA1h, rA1l, rBh, rBl;
    auto loadA = [&](int c) {
        int kglob = c * 32;
        const short *ph, *pl; int st, ko;
        if (kglob < w1) { ph = A1h; pl = A1l; st = s1; ko = kglob; }
        else            { ph = A2h; pl = A2l; st = s2; ko = kglob - w1; }
        size_t o1 = (size_t)ar * st + ko + akg * 8;
        size_t o2 = (size_t)(ar + 128) * st + ko + akg * 8;
        rA0h = *(const short8v*)(ph + o1); rA0l = *(const short8v*)(pl + o1);
        rA1h = *(const short8v*)(ph + o2); rA1l = *(const short8v*)(pl + o2);
    };
    auto loadB = [&](int c) {
        if (tid < 256) {
            size_t o = (size_t)(n0 + br) * KP + c * 32 + bkg * 8;
            if (tid < 128) rBh = *(const short8v*)(Wh + o);
            else           rBl = *(const short8v*)(Wl + o);
        }
    };

    loadA(c0); loadB(c0);
    for (int c = c0; c < c1; ++c) {
        __syncthreads();
        *(short8v*)&Ash[akg][ar][0]       = rA0h;
        *(short8v*)&Asl[akg][ar][0]       = rA0l;
        *(short8v*)&Ash[akg][ar + 128][0] = rA1h;
        *(short8v*)&Asl[akg][ar + 128][0] = rA1l;
        if (tid < 128)      *(short8v*)&Bsh[bkg][br][0] = rBh;
        else if (tid < 256) *(short8v*)&Bsl[bkg][br][0] = rBl;
        if (c + 1 < c1) { loadA(c + 1); loadB(c + 1); }
        __syncthreads();
        short8v ah0 = *(const short8v*)&Ash[kg][wv * 32 + fr][0];
        short8v ah1 = *(const short8v*)&Ash[kg][wv * 32 + 16 + fr][0];
        short8v al0 = *(const short8v*)&Asl[kg][wv * 32 + fr][0];
        short8v al1 = *(const short8v*)&Asl[kg][wv * 32 + 16 + fr][0];
        short8v bh0 = *(const short8v*)&Bsh[kg][fr][0];
        short8v bh1 = *(const short8v*)&Bsh[kg][16 + fr][0];
        short8v bl0 = *(const short8v*)&Bsl[kg][fr][0];
        short8v bl1 = *(const short8v*)&Bsl[kg][16 + fr][0];
        acc[0][0] = __builtin_amdgcn_mfma_f32_16x16x32_bf16(ah0, bh0, acc[0][0], 0, 0, 0);
        acc[0][0] = __builtin_amdgcn_mfma_f32_16x16x32_bf16(ah0, bl0, acc[0][0], 0, 0, 0);
        acc[0][0] = __builtin_amdgcn_mfma_f32_16x16x32_bf16(al0, bh0, acc[0][0], 0, 0, 0);
        acc[0][1] = __builtin_amdgcn_mfma_f32_16x16x32_bf16(ah0, bh1, acc[0][1], 0, 0, 0);
        acc[0][1] = __builtin_amdgcn_mfma_f32_16x16x32_bf16(ah0, bl1, acc[0][1], 0, 0, 0);
        acc[0][1] = __builtin_amdgcn_mfma_f32_16x16x32_bf16(al0, bh1, acc[0][1], 0, 0, 0);
        acc[1][0] = __builtin_amdgcn_mfma_f32_16x16x32_bf16(ah1, bh0, acc[1][0], 0, 0, 0);
        acc[1][0] = __builtin_amdgcn_mfma_f32_16x16x32_bf16(ah1, bl0, acc[1][0], 0, 0, 0);
        acc[1][0] = __builtin_amdgcn_mfma_f32_16x16x32_bf16(al1, bh0, acc[1][0], 0, 0, 0);
        acc[1][1] = __builtin_amdgcn_mfma_f32_16x16x32_bf16(ah1, bh1, acc[1][1], 0, 0, 0);
        acc[1][1] = __builtin_amdgcn_mfma_f32_16x16x32_bf16(ah1, bl1, acc[1][1], 0, 0, 0);
        acc[1][1] = __builtin_amdgcn_mfma_f32_16x16x32_bf16(al1, bh1, acc[1][1], 0, 0, 0);
        __syncthreads();
    }

    #pragma unroll
    for (int mi = 0; mi < 2; ++mi) {
        #pragma unroll
        for (int nf = 0; nf < 2; ++nf) {
            int mb = wv * 32 + mi * 16 + rq;
            int n = n0 + nf * 16 + fr;
            #pragma unroll
            for (int q = 0; q < 4; ++q)
                Gout[((size_t)ks * BB + mb + q) * 4096 + n] = acc[mi][nf][q];
        }
    }
}

// ---------------------------------------------------------------------------
// GRU pointwise combine: sum K-split partials + bias, gates [R|Z|NI|NH],
// h updated in place (fp32 master), hi/lo mirror for next GEMM.
// ---------------------------------------------------------------------------
__global__ __launch_bounds__(1024) void gru_comb(const float* __restrict__ G,
                                                 const float* __restrict__ bp,
                                                 float* __restrict__ h,
                                                 short* __restrict__ hh_,
                                                 short* __restrict__ hl_) {
    int b = blockIdx.x, j = threadIdx.x;
    float r = bp[j], z = bp[HN + j], ni = bp[2 * HN + j], nh = bp[3 * HN + j];
    #pragma unroll
    for (int s = 0; s < KS; ++s) {
        const float* g = G + ((size_t)s * BB + b) * 4096;
        r += g[j]; z += g[HN + j]; ni += g[2 * HN + j]; nh += g[3 * HN + j];
    }
    r = 1.f / (1.f + expf(-r));
    z = 1.f / (1.f + expf(-z));
    float n = tanhf(ni + r * nh);
    size_t off = (size_t)b * HN + j;
    float hn = (1.f - z) * n + z * h[off];
    h[off] = hn;
    short hh, ll; fsplit(hn, hh, ll);
    hh_[off] = hh; hl_[off] = ll;
}

// ---------------------------------------------------------------------------
// Split-bf16 MFMA GEMM (general, 32x64 tile) — encoder + decoder smalls.
// EPI: 0 bias->f32 | 1 bias->pair | 2 relu(v+bias)+addm->pair | 3 relu->f32
// ---------------------------------------------------------------------------
template<int EPI>
__global__ __launch_bounds__(256) void mgemm(
        const float* __restrict__ A0, int a0w, int a0s,
        const short* __restrict__ A1h, const short* __restrict__ A1l, int a1w, int a1s,
        const short* __restrict__ A2h, const short* __restrict__ A2l, int a2w, int a2s,
        const short* __restrict__ Bh, const short* __restrict__ Bl, int KP,
        const float* __restrict__ bias, const float* __restrict__ addm,
        float* __restrict__ Cf, short* __restrict__ Cbh, short* __restrict__ Cbl,
        int N) {
    __shared__ short Ash[32][40];
    __shared__ short Asl[32][40];
    __shared__ short Bsh[64][40];
    __shared__ short Bsl[64][40];
    const int tid = threadIdx.x;
    const int m0 = blockIdx.x * 32, n0 = blockIdx.y * 64;
    const int ra = tid >> 3, ka = (tid & 7) * 4;
    const int rb = tid >> 2, kb = (tid & 3) * 8;
    const int lane = tid & 63, wv = tid >> 6;
    const int wm = (wv & 1) * 16, wn = (wv >> 1) * 32;
    const int fr = lane & 15, fo = (lane >> 4) * 8;
    const int a01 = a0w + a1w, a012 = a01 + a2w;
    f32x4 acc0 = {0.f, 0.f, 0.f, 0.f}, acc1 = {0.f, 0.f, 0.f, 0.f};

    auto ldA = [&](int k, short& hh, short& ll) {
        if (k < a0w) {
            fsplit(A0[(size_t)(m0 + ra) * a0s + k], hh, ll);
        } else if (k < a01) {
            size_t o = (size_t)(m0 + ra) * a1s + (k - a0w);
            hh = A1h[o]; ll = A1l[o];
        } else if (k < a012) {
            size_t o = (size_t)(m0 + ra) * a2s + (k - a01);
            hh = A2h[o]; ll = A2l[o];
        } else { hh = 0; ll = 0; }
    };

    short avh[4], avl[4];
    short8v bvh, bvl;
    #pragma unroll
    for (int j = 0; j < 4; ++j) ldA(ka + j, avh[j], avl[j]);
    bvh = *(const short8v*)(Bh + (size_t)(n0 + rb) * KP + kb);
    bvl = *(const short8v*)(Bl + (size_t)(n0 + rb) * KP + kb);

    for (int k0 = 0; k0 < KP; k0 += 32) {
        #pragma unroll
        for (int j = 0; j < 4; ++j) { Ash[ra][ka + j] = avh[j]; Asl[ra][ka + j] = avl[j]; }
        *(short8v*)&Bsh[rb][kb] = bvh;
        *(short8v*)&Bsl[rb][kb] = bvl;
        int kn = k0 + 32;
        if (kn < KP) {
            #pragma unroll
            for (int j = 0; j < 4; ++j) ldA(kn + ka + j, avh[j], avl[j]);
            bvh = *(const short8v*)(Bh + (size_t)(n0 + rb) * KP + kn + kb);
            bvl = *(const short8v*)(Bl + (size_t)(n0 + rb) * KP + kn + kb);
        }
        __syncthreads();
        short8v ah  = *(const short8v*)&Ash[wm + fr][fo];
        short8v al  = *(const short8v*)&Asl[wm + fr][fo];
        short8v b0h = *(const short8v*)&Bsh[wn + fr][fo];
        short8v b0l = *(const short8v*)&Bsl[wn + fr][fo];
        short8v b1h = *(const short8v*)&Bsh[wn + 16 + fr][fo];
        short8v b1l = *(const short8v*)&Bsl[wn + 16 + fr][fo];
        acc0 = __builtin_amdgcn_mfma_f32_16x16x32_bf16(ah, b0h, acc0, 0, 0, 0);
        acc0 = __builtin_amdgcn_mfma_f32_16x16x32_bf16(ah, b0l, acc0, 0, 0, 0);
        acc0 = __builtin_amdgcn_mfma_f32_16x16x32_bf16(al, b0h, acc0, 0, 0, 0);
        acc1 = __builtin_amdgcn_mfma_f32_16x16x32_bf16(ah, b1h, acc1, 0, 0, 0);
        acc1 = __builtin_amdgcn_mfma_f32_16x16x32_bf16(ah, b1l, acc1, 0, 0, 0);
        acc1 = __builtin_amdgcn_mfma_f32_16x16x32_bf16(al, b1h, acc1, 0, 0, 0);
        __syncthreads();
    }

    const int rq = (lane >> 4) * 4;
    #pragma unroll
    for (int f = 0; f < 2; ++f) {
        f32x4 acc = f ? acc1 : acc0;
        int n = n0 + wn + f * 16 + fr;
        float bb = bias[n];
        #pragma unroll
        for (int q = 0; q < 4; ++q) {
            int m = m0 + wm + rq + q;
            size_t off = (size_t)m * N + n;
            float v = acc[q] + bb;
            if (EPI == 0) {
                Cf[off] = v;
            } else if (EPI == 1) {
                short hh, ll; fsplit(v, hh, ll);
                Cbh[off] = hh; Cbl[off] = ll;
            } else if (EPI == 2) {
                v = fmaxf(v, 0.f) + addm[off];
                short hh, ll; fsplit(v, hh, ll);
                Cbh[off] = hh; Cbl[off] = ll;
            } else {
                Cf[off] = fmaxf(v, 0.f);
            }
        }
    }
}

// ---------------------------------------------------------------------------
// attention (one block per (batch, head)); accumulates mean_t(o) into obar
// ---------------------------------------------------------------------------
__global__ __launch_bounds__(256) void attn_kernel(const float* __restrict__ qkv,
                                                   float* __restrict__ obar, int b0) {
    __shared__ float Qs[FN][DH];
    __shared__ float Ks[FN][DH];
    __shared__ float Ss[FN][62];
    const int bl = blockIdx.x, h = blockIdx.y;
    const float* base = qkv + (size_t)bl * FN * 3 * HN + h * DH;
    for (int i = threadIdx.x; i < FN * DH; i += 256) {
        int t = i >> 8, d = i & 255;
        Qs[t][d] = base[(size_t)t * 3 * HN + d];
        Ks[t][d] = base[(size_t)t * 3 * HN + HN + d];
    }
    __syncthreads();
    for (int p = threadIdx.x; p < FN * FN; p += 256) {
        int qi = p / FN, kj = p - qi * FN;
        const float4* qp = (const float4*)&Qs[qi][0];
        const float4* kp = (const float4*)&Ks[kj][0];
        float s = 0.f;
        #pragma unroll
        for (int c = 0; c < DH / 4; ++c) {
            float4 a = qp[c], b = kp[c];
            s += a.x * b.x + a.y * b.y + a.z * b.z + a.w * b.w;
        }
        Ss[qi][kj] = s * 0.0625f;
    }
    __syncthreads();
    if (threadIdx.x < FN) {
        int qi = threadIdx.x;
        float mx = -1e30f;
        for (int j = 0; j < FN; ++j) mx = fmaxf(mx, Ss[qi][j]);
        float sm = 0.f;
        for (int j = 0; j < FN; ++j) { float e = expf(Ss[qi][j] - mx); Ss[qi][j] = e; sm += e; }
        float inv = 1.f / sm;
        for (int j = 0; j < FN; ++j) Ss[qi][j] *= inv;
    }
    __syncthreads();
    float* Vs = &Qs[0][0];
    for (int i = threadIdx.x; i < FN * DH; i += 256) {
        int t = i >> 8, d = i & 255;
        Vs[t * DH + d] = base[(size_t)t * 3 * HN + 2 * HN + d];
    }
    __syncthreads();
    int d = threadIdx.x;
    float accum = 0.f;
    for (int qi = 0; qi < FN; ++qi) {
        float o = 0.f;
        for (int j = 0; j < FN; ++j) o += Ss[qi][j] * Vs[j * DH + d];
        accum += o;
    }
    obar[(size_t)(b0 + bl) * HN + h * DH + d] = accum * (1.f / (float)FN);
}

// ---------------------------------------------------------------------------
// decoder prep / spl2 / rot6d  (x kept as split pair [256][XWP])
// ---------------------------------------------------------------------------
__global__ __launch_bounds__(128) void prep_kernel(const float* __restrict__ poses,
                                                   float* __restrict__ sixd,
                                                   short* __restrict__ xdh,
                                                   short* __restrict__ xdl) {
    int b = blockIdx.x;
    const float* src = poses + ((size_t)b * TT + (TSEED - 1)) * DN;
    for (int d = threadIdx.x; d < DN; d += 128) {
        short hh, ll; fsplit(src[d], hh, ll);
        xdh[b * XWP + d] = hh; xdl[b * XWP + d] = ll;
    }
    for (int p = threadIdx.x; p < JN * 6; p += 128) {
        int j = p / 6, c = p - j * 6;
        int i = (c < 3) ? c : (c - 3);
        int col = (c < 3) ? 0 : 1;
        sixd[b * JN * 6 + p] = src[j * 9 + i * 3 + col];
    }
}

__global__ __launch_bounds__(128) void spl2_kernel(const float* __restrict__ z1,
                                                   const float* __restrict__ w2,
                                                   const float* __restrict__ b2,
                                                   float* __restrict__ sixd,
                                                   float* __restrict__ out, int t) {
    int b = blockIdx.x, p = threadIdx.x;
    if (p < JN * 6) {
        int j = p / 6, o = p - j * 6;
        const float* z = z1 + (size_t)b * (JN * 128) + j * 128;
        const float* wv = w2 + (j * 6 + o) * 128;
        float s = b2[j * 6 + o];
        #pragma unroll 4
        for (int k = 0; k < 128; ++k) s += z[k] * wv[k];
        float nv = sixd[b * JN * 6 + p] + s;
        sixd[b * JN * 6 + p] = nv;
        out[((size_t)b * PREDN + t) * (JN * 6) + p] = nv;
    }
}

__global__ __launch_bounds__(256) void rot_kernel(const float* __restrict__ sixd,
                                                  short* __restrict__ xdh,
                                                  short* __restrict__ xdl) {
    int i = blockIdx.x * 256 + threadIdx.x;
    if (i >= BB * JN) return;
    int b = i / JN, j = i - b * JN;
    const float* v = sixd + b * JN * 6 + j * 6;
    float a1x = v[0], a1y = v[2], a1z = v[4];
    float a2x = v[1], a2y = v[3], a2z = v[5];
    float n1 = fmaxf(sqrtf(a1x * a1x + a1y * a1y + a1z * a1z), 1e-12f);
    float b1x = a1x / n1, b1y = a1y / n1, b1z = a1z / n1;
    float dt = b1x * a2x + b1y * a2y + b1z * a2z;
    float ox = a2x - dt * b1x, oy = a2y - dt * b1y, oz = a2z - dt * b1z;
    float n2 = fmaxf(sqrtf(ox * ox + oy * oy + oz * oz), 1e-12f);
    float b2x = ox / n2, b2y = oy / n2, b2z = oz / n2;
    float b3x = b1y * b2z - b1z * b2y;
    float b3y = b1z * b2x - b1x * b2z;
    float b3z = b1x * b2y - b1y * b2x;
    float r9[9] = {b1x, b2x, b3x, b1y, b2y, b3y, b1z, b2z, b3z};
    short* oh = xdh + (size_t)b * XWP + j * 9;
    short* ol = xdl + (size_t)b * XWP + j * 9;
    #pragma unroll
    for (int q = 0; q < 9; ++q) {
        short hh, ll; fsplit(r9[q], hh, ll);
        oh[q] = hh; ol[q] = ll;
    }
}

// ---------------------------------------------------------------------------
extern "C" void kernel_launch(void* const* d_in, const int* in_sizes, int n_in,
                              void* d_out, int out_size, void* d_ws, size_t ws_size,
                              hipStream_t stream) {
    const float* poses  = (const float*)d_in[0];
    const float* freq_w = (const float*)d_in[1];
    const float* freq_b = (const float*)d_in[2];
    const float* ain_w  = (const float*)d_in[3];
    const float* ain_b  = (const float*)d_in[4];
    const float* aout_w = (const float*)d_in[5];
    const float* aout_b = (const float*)d_in[6];
    const float* wih0   = (const float*)d_in[7];
    const float* whh0   = (const float*)d_in[8];
    const float* bih0   = (const float*)d_in[9];
    const float* bhh0   = (const float*)d_in[10];
    const float* wih1   = (const float*)d_in[11];
    const float* whh1   = (const float*)d_in[12];
    const float* bih1   = (const float*)d_in[13];
    const float* bhh1   = (const float*)d_in[14];
    const float* pre_w  = (const float*)d_in[15];
    const float* pre_b  = (const float*)d_in[16];
    const float* spl_w1 = (const float*)d_in[17];
    const float* spl_b1 = (const float*)d_in[18];
    const float* spl_w2 = (const float*)d_in[19];
    const float* spl_b2 = (const float*)d_in[20];
    float* out = (float*)d_out;

    char* p = (char*)d_ws;
    auto alloc = [&](size_t bytes) { void* r = p; p += (bytes + 255) & ~(size_t)255; return r; };
    short* W0h    = (short*)alloc((size_t)4096 * KP0 * 2);
    short* W0l    = (short*)alloc((size_t)4096 * KP0 * 2);
    short* W1h    = (short*)alloc((size_t)4096 * KP1 * 2);
    short* W1l    = (short*)alloc((size_t)4096 * KP1 * 2);
    float* b0p    = (float*)alloc(4096 * 4);
    float* b1p    = (float*)alloc(4096 * 4);
    short* freqh  = (short*)alloc((size_t)1024 * KPF * 2);
    short* freql  = (short*)alloc((size_t)1024 * KPF * 2);
    short* ainh   = (short*)alloc((size_t)3072 * 1024 * 2);
    short* ainl   = (short*)alloc((size_t)3072 * 1024 * 2);
    short* aouth  = (short*)alloc((size_t)1024 * 1024 * 2);
    short* aoutl  = (short*)alloc((size_t)1024 * 1024 * 2);
    short* preh   = (short*)alloc((size_t)1024 * 1024 * 2);
    short* prel   = (short*)alloc((size_t)1024 * 1024 * 2);
    short* spl1h  = (short*)alloc((size_t)1920 * 1024 * 2);
    short* spl1l  = (short*)alloc((size_t)1920 * 1024 * 2);
    short* Xh     = (short*)alloc((size_t)TSEED * BB * XWP * 2);
    short* Xl     = (short*)alloc((size_t)TSEED * BB * XWP * 2);
    float* cosm   = (float*)alloc(FN * TSEED * 4);
    float* freqf  = (float*)alloc((size_t)BB * FN * DN * 4);
    short* feath  = (short*)alloc((size_t)RCH * HN * 2);
    short* featl  = (short*)alloc((size_t)RCH * HN * 2);
    float* qkvc   = (float*)alloc((size_t)RCH * 3 * HN * 4);   // 24 MB
    float* G      = qkvc;  // alias: G[KS][256][4096] = 16.8 MB, disjoint lifetime
    float* obar   = (float*)alloc((size_t)BB * HN * 4);
    float* mctx   = (float*)alloc((size_t)BB * HN * 4);
    float* h0     = (float*)alloc((size_t)BB * HN * 4);
    float* h1     = (float*)alloc((size_t)BB * HN * 4);
    short* h0h    = (short*)alloc((size_t)BB * HN * 2);
    short* h0l    = (short*)alloc((size_t)BB * HN * 2);
    short* h1h    = (short*)alloc((size_t)BB * HN * 2);
    short* h1l    = (short*)alloc((size_t)BB * HN * 2);
    short* hidh   = (short*)alloc((size_t)BB * HN * 2);
    short* hidl   = (short*)alloc((size_t)BB * HN * 2);
    float* z1     = (float*)alloc((size_t)BB * JN * 128 * 4);
    float* sixd   = (float*)alloc((size_t)BB * JN * 6 * 4);
    short* xdh    = (short*)alloc((size_t)BB * XWP * 2);
    short* xdl    = (short*)alloc((size_t)BB * XWP * 2);

    // ---- prepack (every call; graph-safe) ----
    pack_gruw<<<4096, 256, 0, stream>>>(wih0, whh0, DN, XWP, KP0, W0h, W0l);
    pack_gruw<<<4096, 256, 0, stream>>>(wih1, whh1, HN, HN, KP1, W1h, W1l);
    pack_grub<<<16, 256, 0, stream>>>(bih0, bhh0, b0p);
    pack_grub<<<16, 256, 0, stream>>>(bih1, bhh1, b1p);
    castw<<<1024, 256, 0, stream>>>(freq_w, freqh, freql, DN, KPF);
    castw<<<3072, 256, 0, stream>>>(ain_w, ainh, ainl, HN, HN);
    castw<<<1024, 256, 0, stream>>>(aout_w, aouth, aoutl, HN, HN);
    castw<<<1024, 256, 0, stream>>>(pre_w, preh, prel, HN, HN);
    castw<<<1920, 256, 0, stream>>>(spl_w1, spl1h, spl1l, HN, HN);
    pack_x<<<TSEED, 256, 0, stream>>>(poses, Xh, Xl);

    // ---- encoder ----
    cos_kernel<<<FN, 128, 0, stream>>>(cosm);
    dft_kernel<<<BB, 256, 0, stream>>>(poses, cosm, freqf);
    for (int bc = 0; bc < BB / BCH; ++bc) {
        mgemm<1><<<dim3(RCH / 32, HN / 64), 256, 0, stream>>>(
            freqf + (size_t)bc * RCH * DN, DN, DN,
            nullptr, nullptr, 0, 0, nullptr, nullptr, 0, 0,
            freqh, freql, KPF, freq_b, nullptr, nullptr, feath, featl, HN);
        mgemm<0><<<dim3(RCH / 32, 3 * HN / 64), 256, 0, stream>>>(
            nullptr, 0, 0, feath, featl, HN, HN, nullptr, nullptr, 0, 0,
            ainh, ainl, HN, ain_b, nullptr, qkvc, nullptr, nullptr, 3 * HN);
        attn_kernel<<<dim3(BCH, 4), 256, 0, stream>>>(qkvc, obar, bc * BCH);
    }
    mgemm<0><<<dim3(BB / 32, HN / 64), 256, 0, stream>>>(
        obar, HN, HN, nullptr, nullptr, 0, 0, nullptr, nullptr, 0, 0,
        aouth, aoutl, HN, aout_b, nullptr, mctx, nullptr, nullptr, HN);

    // ---- GRU encoder: BM=256 K-split GEMM + combine, 120 steps ----
    hipMemsetAsync(h0, 0, (size_t)BB * HN * 4, stream);
    hipMemsetAsync(h1, 0, (size_t)BB * HN * 4, stream);
    hipMemsetAsync(h0h, 0, (size_t)BB * HN * 2, stream);
    hipMemsetAsync(h0l, 0, (size_t)BB * HN * 2, stream);
    hipMemsetAsync(h1h, 0, (size_t)BB * HN * 2, stream);
    hipMemsetAsync(h1l, 0, (size_t)BB * HN * 2, stream);
    dim3 ggrid(KS, 4096 / 32);
    for (int t = 0; t < TSEED; ++t) {
        ggemm<<<ggrid, 512, 0, stream>>>(
            Xh + (size_t)t * BB * XWP, Xl + (size_t)t * BB * XWP, XWP, XWP,
            h0h, h0l, HN, W0h, W0l, KP0, KP0 / 32, G);
        gru_comb<<<BB, 1024, 0, stream>>>(G, b0p, h0, h0h, h0l);
        ggemm<<<ggrid, 512, 0, stream>>>(
            h0h, h0l, HN, HN, h1h, h1l, HN, W1h, W1l, KP1, KP1 / 32, G);
        gru_comb<<<BB, 1024, 0, stream>>>(G, b1p, h1, h1h, h1l);
    }

    // ---- decoder ----
    hipMemsetAsync(xdh, 0, (size_t)BB * XWP * 2, stream);
    hipMemsetAsync(xdl, 0, (size_t)BB * XWP * 2, stream);
    prep_kernel<<<BB, 128, 0, stream>>>(poses, sixd, xdh, xdl);
    for (int t = 0; t < PREDN; ++t) {
        ggemm<<<ggrid, 512, 0, stream>>>(
            xdh, xdl, XWP, XWP, h0h, h0l, HN, W0h, W0l, KP0, KP0 / 32, G);
        gru_comb<<<BB, 1024, 0, stream>>>(G, b0p, h0, h0h, h0l);
        ggemm<<<ggrid, 512, 0, stream>>>(
            h0h, h0l, HN, HN, h1h, h1l, HN, W1h, W1l, KP1, KP1 / 32, G);
        gru_comb<<<BB, 1024, 0, stream>>>(G, b1p, h1, h1h, h1l);
        mgemm<2><<<dim3(BB / 32, HN / 64), 256, 0, stream>>>(
            nullptr, 0, 0, h1h, h1l, HN, HN, nullptr, nullptr, 0, 0,
            preh, prel, HN, pre_b, mctx, nullptr, hidh, hidl, HN);
        mgemm<3><<<dim3(BB / 32, 1920 / 64), 256, 0, stream>>>(
            nullptr, 0, 0, hidh, hidl, HN, HN, nullptr, nullptr, 0, 0,
            spl1h, spl1l, HN, spl_b1, nullptr, z1, nullptr, nullptr, 1920);
        spl2_kernel<<<BB, 128, 0, stream>>>(z1, spl_w2, spl_b2, sixd, out, t);
        rot_kernel<<<(BB * JN + 255) / 256, 256, 0, stream>>>(sixd, xdh, xdl);
    }
}